// Round 1
// baseline (651.027 us; speedup 1.0000x reference)
//
#include <hip/hip_runtime.h>

// B=64, C=2, N=1024, T=13, D=256
// out: [B,N,N] fp32 = 268 MB; ws: centered ranks as bf16 bits [B,N,D] u16 = 32 MB

typedef __attribute__((ext_vector_type(4))) float f32x4;
typedef __attribute__((ext_vector_type(8))) short bf16x8;

__device__ __forceinline__ void load_lds16(const void* g, void* l) {
  __builtin_amdgcn_global_load_lds(
      (const __attribute__((address_space(1))) void*)g,
      (__attribute__((address_space(3))) void*)l, 16, 0, 0);
}

// ---------------------------------------------------------------------------
// K1: conv (bcnt,dct->bnd) + time-LayerNorm + Spearman rank -> (rank-128) bf16
// one block (256 threads) per (b,n) row; thread d owns dim d.
// ---------------------------------------------------------------------------
__global__ __launch_bounds__(256) void conv_rank_kernel(
    const float* __restrict__ x, const float* __restrict__ w,
    const float* __restrict__ cb, const float* __restrict__ tg,
    const float* __restrict__ tb, unsigned short* __restrict__ ranks)
{
  int row = blockIdx.x;              // b*1024 + n
  int b = row >> 10, n = row & 1023;
  int d = threadIdx.x;
  int wave = d >> 6, lane = d & 63;

  __shared__ float xs[26];
  __shared__ float red[8];
  __shared__ __align__(16) unsigned int ks[256];

  if (d < 26) {
    int c = d / 13, t = d - c * 13;
    xs[d] = x[((size_t)(b * 2 + c) * 1024 + n) * 13 + t];
  }
  __syncthreads();

  // conv: emb_d = cb[d] + sum_{c,t} w[d,c,t] * x[b,c,n,t]  (i = c*13+t)
  const float* wd = w + d * 26;
  float acc = cb[d];
  #pragma unroll
  for (int i = 0; i < 26; ++i) acc += wd[i] * xs[i];

  // time layernorm over D=256 (one value per thread)
  float v1 = acc, v2 = acc * acc;
  #pragma unroll
  for (int o = 32; o > 0; o >>= 1) {
    v1 += __shfl_down(v1, o);
    v2 += __shfl_down(v2, o);
  }
  if (lane == 0) { red[wave * 2] = v1; red[wave * 2 + 1] = v2; }
  __syncthreads();
  float s1 = red[0] + red[2] + red[4] + red[6];
  float s2 = red[1] + red[3] + red[5] + red[7];
  float mu = s1 * (1.0f / 256.0f);
  float var = s2 * (1.0f / 256.0f) - mu * mu;
  float rs = rsqrtf(var + 1e-5f);
  float val = (acc - mu) * rs * tg[d] + tb[d];

  // monotone sortable u32 key
  unsigned int u = __float_as_uint(val);
  unsigned int key = (u & 0x80000000u) ? ~u : (u | 0x80000000u);
  ks[d] = key;
  __syncthreads();

  // rank_d = #{j : key_j < key_d}   (exact fp32 ties ~ prob 0; error << threshold)
  int cnt = 0;
  const uint4* k4 = (const uint4*)ks;
  #pragma unroll 8
  for (int j = 0; j < 64; ++j) {
    uint4 kk = k4[j];   // LDS broadcast b128
    cnt += (int)(kk.x < key) + (int)(kk.y < key) +
           (int)(kk.z < key) + (int)(kk.w < key);
  }

  // store r' = rank - 128 in [-128,127]: exact in bf16 (low 16 fp32 bits are 0)
  float rv = (float)(cnt - 128);
  ranks[(size_t)row * 256 + d] = (unsigned short)(__float_as_uint(rv) >> 16);
}

// ---------------------------------------------------------------------------
// K2: per batch S = R R^T (1024x1024x256 bf16 MFMA), adj = |S-64| / (norm^2+1e-8)
// m97 structure: 128x128 tile, BK=64, global_load_lds width 16, 4 waves x (64x64)
// ---------------------------------------------------------------------------
__global__ __launch_bounds__(256) void corr_kernel(
    const unsigned short* __restrict__ ranks, float* __restrict__ out)
{
  int blk = blockIdx.x;
  int b = blk >> 6;
  int tile = blk & 63;
  int trow = (tile >> 3) << 7;
  int tcol = (tile & 7) << 7;
  const unsigned short* R = ranks + (size_t)b * 1024 * 256;
  float* O = out + (size_t)b * 1024 * 1024;

  __shared__ __align__(16) unsigned short As[128 * 64];
  __shared__ __align__(16) unsigned short Bs[128 * 64];

  int tid = threadIdx.x;
  int wave = tid >> 6, lane = tid & 63;
  int wrow = (wave >> 1) * 64, wcol = (wave & 1) * 64;

  f32x4 acc[4][4] = {};

  for (int kt = 0; kt < 4; ++kt) {
    int k0 = kt * 64;
    #pragma unroll
    for (int q = 0; q < 4; ++q) {
      int elem = q * 2048 + tid * 8;   // wave-contiguous: base + lane*8 elems
      int r = elem >> 6;
      int c = elem & 63;
      load_lds16(R + (size_t)(trow + r) * 256 + k0 + c, As + elem);
      load_lds16(R + (size_t)(tcol + r) * 256 + k0 + c, Bs + elem);
    }
    __syncthreads();   // compiler drains vmcnt before s_barrier

    #pragma unroll
    for (int ks2 = 0; ks2 < 2; ++ks2) {
      int kk = ks2 * 32 + ((lane >> 4) << 3);   // A/B frag: k = quad*8 + j
      bf16x8 af[4], bf[4];
      #pragma unroll
      for (int mi = 0; mi < 4; ++mi)
        af[mi] = *(const bf16x8*)(As + (wrow + mi * 16 + (lane & 15)) * 64 + kk);
      #pragma unroll
      for (int ni = 0; ni < 4; ++ni)
        bf[ni] = *(const bf16x8*)(Bs + (wcol + ni * 16 + (lane & 15)) * 64 + kk);
      #pragma unroll
      for (int mi = 0; mi < 4; ++mi) {
        #pragma unroll
        for (int ni = 0; ni < 4; ++ni)
          acc[mi][ni] = __builtin_amdgcn_mfma_f32_16x16x32_bf16(
              af[mi], bf[ni], acc[mi][ni], 0, 0, 0);
      }
    }
    __syncthreads();
  }

  // corr = S - 64 (exact); denom = norm*norm + 1e-8, norm = sqrt(1398080)
  float nrm = sqrtf(1398080.0f);
  float inv_den = 1.0f / (nrm * nrm + 1e-8f);
  #pragma unroll
  for (int mi = 0; mi < 4; ++mi) {
    int r0 = trow + wrow + mi * 16 + ((lane >> 4) << 2);  // C/D: row=quad*4+reg
    #pragma unroll
    for (int ni = 0; ni < 4; ++ni) {
      int c0 = tcol + wcol + ni * 16 + (lane & 15);       // C/D: col=lane&15
      #pragma unroll
      for (int v = 0; v < 4; ++v) {
        float adj = fabsf(acc[mi][ni][v] - 64.0f) * inv_den;
        O[(size_t)(r0 + v) * 1024 + c0] = adj;
      }
    }
  }
}

// ---------------------------------------------------------------------------
// K3: in-place LayerNorm over last axis (N=1024) + static_g/static_b + ReLU
// one block per row, thread = one float4
// ---------------------------------------------------------------------------
__global__ __launch_bounds__(256) void ln_relu_kernel(
    float* __restrict__ out, const float* __restrict__ sg,
    const float* __restrict__ sb)
{
  size_t row = blockIdx.x;
  float* p = out + row * 1024;
  int tid = threadIdx.x;
  int wave = tid >> 6, lane = tid & 63;

  float4 v = ((float4*)p)[tid];
  float s1 = v.x + v.y + v.z + v.w;
  float s2 = v.x * v.x + v.y * v.y + v.z * v.z + v.w * v.w;
  #pragma unroll
  for (int o = 32; o > 0; o >>= 1) {
    s1 += __shfl_down(s1, o);
    s2 += __shfl_down(s2, o);
  }
  __shared__ float red[8];
  if (lane == 0) { red[wave * 2] = s1; red[wave * 2 + 1] = s2; }
  __syncthreads();
  float t1 = red[0] + red[2] + red[4] + red[6];
  float t2 = red[1] + red[3] + red[5] + red[7];
  float mu = t1 * (1.0f / 1024.0f);
  float var = t2 * (1.0f / 1024.0f) - mu * mu;
  float rs = rsqrtf(var + 1e-5f);

  float4 g = ((const float4*)sg)[tid];
  float4 bb = ((const float4*)sb)[tid];
  v.x = fmaxf(0.0f, (v.x - mu) * rs * g.x + bb.x);
  v.y = fmaxf(0.0f, (v.y - mu) * rs * g.y + bb.y);
  v.z = fmaxf(0.0f, (v.z - mu) * rs * g.z + bb.z);
  v.w = fmaxf(0.0f, (v.w - mu) * rs * g.w + bb.w);
  ((float4*)p)[tid] = v;
}

extern "C" void kernel_launch(void* const* d_in, const int* in_sizes, int n_in,
                              void* d_out, int out_size, void* d_ws, size_t ws_size,
                              hipStream_t stream) {
  const float* x  = (const float*)d_in[0];
  const float* w  = (const float*)d_in[1];
  const float* cb = (const float*)d_in[2];
  const float* tg = (const float*)d_in[3];
  const float* tb = (const float*)d_in[4];
  const float* sg = (const float*)d_in[5];
  const float* sb = (const float*)d_in[6];
  float* out = (float*)d_out;
  unsigned short* ranks = (unsigned short*)d_ws;  // needs 64*1024*256*2 = 32 MB

  conv_rank_kernel<<<64 * 1024, 256, 0, stream>>>(x, w, cb, tg, tb, ranks);
  corr_kernel<<<64 * 64, 256, 0, stream>>>(ranks, out);
  ln_relu_kernel<<<64 * 1024, 256, 0, stream>>>(out, sg, sb);
}